// Round 2
// baseline (600.054 us; speedup 1.0000x reference)
//
#include <hip/hip_runtime.h>

#define KMASK (-2.3819763e38f)

typedef __attribute__((ext_vector_type(8))) _Float16 f16x8;
typedef __attribute__((ext_vector_type(4))) _Float16 f16x4;
typedef __attribute__((ext_vector_type(4))) float f32x4;

// async global->LDS, 16B per lane. LDS dest must be wave-uniform base (+lane*16 implicit).
__device__ __forceinline__ void gload_lds16(const void* g, void* lds) {
    __builtin_amdgcn_global_load_lds(
        (__attribute__((address_space(1))) void*)(g),
        (__attribute__((address_space(3))) void*)(lds), 16, 0, 0);
}

// 50 * tanh(x / 50), fast: tanh(a) = (1 - e^{-2a}) / (1 + e^{-2a}), sign-restored.
__device__ __forceinline__ float softcap50(float x) {
    const float t = __expf(-0.04f * fabsf(x));
    const float r = (1.f - t) * __builtin_amdgcn_rcpf(1.f + t);
    return copysignf(50.f * r, x);
}

// ---------------------------------------------------------------------------
// RoPE table: ct/st[s][f] = cos/sin(s * theta^(-2f/256)), f in [0,128)
// ---------------------------------------------------------------------------
__global__ void rope_tab(float* __restrict__ ct, float* __restrict__ st) {
    const int s = blockIdx.x, f = threadIdx.x;
    const float inv = powf(10000.f, -2.f * (float)f / 256.f);
    const float a = (float)s * inv;
    ct[s * 128 + f] = cosf(a);
    st[s * 128 + f] = sinf(a);
}

// ---------------------------------------------------------------------------
// f32 -> f16 elementwise (4/thread)
// ---------------------------------------------------------------------------
__global__ void conv16(const float* __restrict__ x, _Float16* __restrict__ y) {
    const size_t i = ((size_t)blockIdx.x * 256 + threadIdx.x) * 4;
    const float4 v = *(const float4*)(x + i);
    f16x4 o;
    o.x = (_Float16)v.x; o.y = (_Float16)v.y; o.z = (_Float16)v.z; o.w = (_Float16)v.w;
    *(f16x4*)(y + i) = o;
}

// ---------------------------------------------------------------------------
// Tiled transpose + convert: W[K][N] f32 -> WT[N][K] f16
// ---------------------------------------------------------------------------
__global__ void tconv(const float* __restrict__ W, _Float16* __restrict__ WT, int K, int N) {
    __shared__ float t[32][33];
    const int n0 = blockIdx.x * 32, k0 = blockIdx.y * 32;
    const int tx = threadIdx.x, ty = threadIdx.y;
#pragma unroll
    for (int i = ty; i < 32; i += 8) t[i][tx] = W[(size_t)(k0 + i) * N + n0 + tx];
    __syncthreads();
#pragma unroll
    for (int i = ty; i < 32; i += 8) WT[(size_t)(n0 + i) * K + k0 + tx] = (_Float16)t[tx][i];
}

// ---------------------------------------------------------------------------
// GEMM: C[M][N] (f32) = A[M][K] (f16, row-major) @ BT[N][K]^T (f16)
// 128x128 tile, BK=32, 4 waves (2x2), 16x16x32 MFMA, global_load_lds staging.
// ---------------------------------------------------------------------------
__global__ __launch_bounds__(256) void gemm_f16(
    const _Float16* __restrict__ A, const _Float16* __restrict__ BT,
    float* __restrict__ C, int M, int N, int K) {
    __shared__ _Float16 As[128 * 32];
    __shared__ _Float16 Bs[128 * 32];
    const int tid = threadIdx.x;
    const int l = tid & 63, w = tid >> 6;
    const int lr = l & 15, lg4 = l >> 4;
    const int wr = w >> 1, wc = w & 1;
    const size_t bm = (size_t)blockIdx.y * 128, bn = (size_t)blockIdx.x * 128;

    f32x4 acc[4][4];
#pragma unroll
    for (int i = 0; i < 4; i++)
#pragma unroll
        for (int j = 0; j < 4; j++) acc[i][j] = (f32x4){0.f, 0.f, 0.f, 0.f};

    for (int k0 = 0; k0 < K; k0 += 32) {
#pragma unroll
        for (int i = 0; i < 2; i++) {
            const int o = w * 2048 + i * 1024 + l * 16;  // byte offset into 8KB tile
            const int row = o >> 6;                      // 64B per LDS row (32 f16)
            const int ce = (o & 63) >> 1;                // element within row
            gload_lds16(A + (bm + row) * (size_t)K + k0 + ce, (char*)As + (o - l * 16));
            gload_lds16(BT + (bn + row) * (size_t)K + k0 + ce, (char*)Bs + (o - l * 16));
        }
        asm volatile("s_waitcnt vmcnt(0)" ::: "memory");
        __syncthreads();

        f16x8 af[4], bfr[4];
#pragma unroll
        for (int mm = 0; mm < 4; mm++)
            af[mm] = *(const f16x8*)(As + (wr * 64 + mm * 16 + lr) * 32 + lg4 * 8);
#pragma unroll
        for (int nn = 0; nn < 4; nn++)
            bfr[nn] = *(const f16x8*)(Bs + (wc * 64 + nn * 16 + lr) * 32 + lg4 * 8);
#pragma unroll
        for (int mm = 0; mm < 4; mm++)
#pragma unroll
            for (int nn = 0; nn < 4; nn++)
                acc[mm][nn] = __builtin_amdgcn_mfma_f32_16x16x32_f16(af[mm], bfr[nn], acc[mm][nn], 0, 0, 0);
        __syncthreads();
    }
#pragma unroll
    for (int mm = 0; mm < 4; mm++)
#pragma unroll
        for (int nn = 0; nn < 4; nn++)
#pragma unroll
            for (int r = 0; r < 4; r++) {
                const size_t rr = bm + wr * 64 + mm * 16 + lg4 * 4 + r;
                const size_t cc = bn + wc * 64 + nn * 16 + lr;
                C[rr * N + cc] = acc[mm][nn][r];
            }
}

// ---------------------------------------------------------------------------
// RMSNorm * (1+scale) + RoPE for q/k, reading from fused QKV f32 buffer.
// x row = qkv[s][colbase + h*256 + :256]. out layout: [h][s][256] f16.
// ---------------------------------------------------------------------------
__global__ __launch_bounds__(256) void norm_rope(
    const float* __restrict__ x, int colbase, int logh,
    const float* __restrict__ scale,
    const float* __restrict__ ct, const float* __restrict__ st,
    _Float16* __restrict__ out) {
    const int w = threadIdx.x >> 6, l = threadIdx.x & 63;
    const int row = blockIdx.x * 4 + w;
    const int s = row >> logh, h = row & ((1 << logh) - 1);
    const float4 v = *(const float4*)(x + (size_t)s * 4096 + colbase + h * 256 + l * 4);
    float ss = v.x * v.x + v.y * v.y + v.z * v.z + v.w * v.w;
#pragma unroll
    for (int mm = 1; mm < 64; mm <<= 1) ss += __shfl_xor(ss, mm);
    const float r = rsqrtf(ss * (1.f / 256.f) + 1e-6f);
    const float4 sc = *(const float4*)(scale + l * 4);
    float y0 = v.x * r * (1.f + sc.x), y1 = v.y * r * (1.f + sc.y);
    float y2 = v.z * r * (1.f + sc.z), y3 = v.w * r * (1.f + sc.w);
    // RoPE
    const float p0 = __shfl_xor(y0, 32), p1 = __shfl_xor(y1, 32);
    const float p2 = __shfl_xor(y2, 32), p3 = __shfl_xor(y3, 32);
    const int f = (l & 31) * 4;
    const float4 c = *(const float4*)(ct + (size_t)s * 128 + f);
    const float4 sn = *(const float4*)(st + (size_t)s * 128 + f);
    if (l < 32) {
        y0 = y0 * c.x - p0 * sn.x; y1 = y1 * c.y - p1 * sn.y;
        y2 = y2 * c.z - p2 * sn.z; y3 = y3 * c.w - p3 * sn.w;
    } else {
        y0 = y0 * c.x + p0 * sn.x; y1 = y1 * c.y + p1 * sn.y;
        y2 = y2 * c.z + p2 * sn.z; y3 = y3 * c.w + p3 * sn.w;
    }
    f16x4 o;
    o.x = (_Float16)y0; o.y = (_Float16)y1; o.z = (_Float16)y2; o.w = (_Float16)y3;
    *(f16x4*)(out + ((size_t)h * 4096 + s) * 256 + l * 4) = o;
}

// ---------------------------------------------------------------------------
// V: RMSNorm (no weight) + transpose to vt[kvh][d][s] f16.
// Block: 32 s-rows of one kv head; 4 waves, 8 rows each; LDS tile transpose.
// ---------------------------------------------------------------------------
__global__ __launch_bounds__(256) void norm_v_t(
    const float* __restrict__ x, _Float16* __restrict__ vt) {
    __shared__ _Float16 T[32][256];
    const int tid = threadIdx.x, l = tid & 63, w = tid >> 6;
    const int kvh = blockIdx.y;
    const int s0 = blockIdx.x * 32;
#pragma unroll
    for (int i = 0; i < 8; i++) {
        const int sr = w * 8 + i;
        const float4 v = *(const float4*)(x + (size_t)(s0 + sr) * 4096 + 3072 + kvh * 256 + l * 4);
        float ss = v.x * v.x + v.y * v.y + v.z * v.z + v.w * v.w;
#pragma unroll
        for (int mm = 1; mm < 64; mm <<= 1) ss += __shfl_xor(ss, mm);
        const float r = rsqrtf(ss * (1.f / 256.f) + 1e-6f);
        f16x4 o;
        o.x = (_Float16)(v.x * r); o.y = (_Float16)(v.y * r);
        o.z = (_Float16)(v.z * r); o.w = (_Float16)(v.w * r);
        *(f16x4*)(&T[sr][l * 4]) = o;
    }
    __syncthreads();
    const int d = tid;  // 0..255
#pragma unroll
    for (int u = 0; u < 4; u++) {
        f16x8 b;
#pragma unroll
        for (int e = 0; e < 8; e++) b[e] = T[u * 8 + e][d];
        *(f16x8*)(vt + ((size_t)kvh * 256 + d) * 4096 + s0 + u * 8) = b;
    }
}

// ---------------------------------------------------------------------------
// Flash attention, swapped-QK^T structure. GQA (NH=8, NKV=4), window 1024,
// softcap 50. Grid (S/64, NH); block 256 = 4 independent waves (NO barriers),
// wave w owns q rows blk*64 + w*16 .. +15.
// q/k head-major f16 [h][s][256]; V transposed f16 [kvh][d][s].
// S^T = mfma(K, Q): lane (lr,g) holds S[key=kt+4g+r(+16)][q=qs+lr] -> softmax
// state (m,lsum) is scalar per lane. P -> A-frag via tiny per-wave LDS.
// ---------------------------------------------------------------------------
__global__ __launch_bounds__(256, 2) void attn_fwd(
    const _Float16* __restrict__ qn, const _Float16* __restrict__ kn,
    const _Float16* __restrict__ vt, _Float16* __restrict__ attnout) {
    __shared__ _Float16 Parr[4][16 * 36];  // per-wave P buffer, stride 36 (pad)
    const int tid = threadIdx.x, l = tid & 63, w = tid >> 6;
    const int lr = l & 15, g = l >> 4;
    const int h = blockIdx.y, kvh = h >> 1;
    const int qs = blockIdx.x * 64 + w * 16;  // this wave's q-row start
    const int q = qs + lr;                    // this lane's softmax row

    // Q fragments (B-operand): lane holds Q[q][d = c*32 + g*8 + j]
    f16x8 qfr[8];
    {
        const _Float16* qp = qn + ((size_t)h * 4096 + qs + lr) * 256 + g * 8;
#pragma unroll
        for (int c = 0; c < 8; c++) qfr[c] = *(const f16x8*)(qp + c * 32);
    }
    f32x4 Of[16];
#pragma unroll
    for (int i = 0; i < 16; i++) Of[i] = (f32x4){0.f, 0.f, 0.f, 0.f};
    float m = KMASK, lsum = 0.f;

    const int kt0 = (qs >= 1024) ? ((qs - 1023) & ~31) : 0;
    const int ktend = qs + 16;
    _Float16* pw = &Parr[w][0];
    const _Float16* vbase = vt + (size_t)kvh * 256 * 4096;

    for (int kt = kt0; kt < ktend; kt += 32) {
        // --- QK^T (swapped): lgf0 keys kt+4g+r, lgf1 keys kt+16+4g+r, col q=lr
        f32x4 lgf0 = (f32x4){0.f, 0.f, 0.f, 0.f};
        f32x4 lgf1 = (f32x4){0.f, 0.f, 0.f, 0.f};
        const _Float16* kp = kn + ((size_t)kvh * 4096 + kt + lr) * 256 + g * 8;
#pragma unroll
        for (int c = 0; c < 8; c++) {
            const f16x8 k0 = *(const f16x8*)(kp + c * 32);
            const f16x8 k1 = *(const f16x8*)(kp + 16 * 256 + c * 32);
            lgf0 = __builtin_amdgcn_mfma_f32_16x16x32_f16(k0, qfr[c], lgf0, 0, 0, 0);
            lgf1 = __builtin_amdgcn_mfma_f32_16x16x32_f16(k1, qfr[c], lgf1, 0, 0, 0);
        }

        // --- softcap + mask (per-lane, row q) ---
        float c0[4], c1[4];
#pragma unroll
        for (int r = 0; r < 4; r++) {
            const int key0 = kt + 4 * g + r, key1 = key0 + 16;
            const float t0 = softcap50(lgf0[r]);
            const float t1 = softcap50(lgf1[r]);
            c0[r] = (key0 <= q && q - key0 < 1024) ? t0 : KMASK;
            c1[r] = (key1 <= q && q - key1 < 1024) ? t1 : KMASK;
        }
        // row max over 32 keys: 8 in-lane + across the 4 g-groups (lanes ^16, ^32)
        float mx = fmaxf(fmaxf(fmaxf(c0[0], c0[1]), fmaxf(c0[2], c0[3])),
                         fmaxf(fmaxf(c1[0], c1[1]), fmaxf(c1[2], c1[3])));
        mx = fmaxf(mx, __shfl_xor(mx, 16));
        mx = fmaxf(mx, __shfl_xor(mx, 32));
        // T13 defer-max: only rescale when max grows by > 8
        const bool need = mx > m + 8.f;
        float scale = 1.f;
        if (need) { scale = __expf(m - mx); m = mx; }
        // P = exp(c - m): masked entries give exp(KMASK - m) == 0 automatically
        float p0[4], p1[4];
        float ps = 0.f;
#pragma unroll
        for (int r = 0; r < 4; r++) {
            p0[r] = __expf(c0[r] - m);
            p1[r] = __expf(c1[r] - m);
            ps += p0[r] + p1[r];
        }
        ps += __shfl_xor(ps, 16);
        ps += __shfl_xor(ps, 32);
        lsum = lsum * scale + ps;
        if (__any(need)) {
            float sr[4];
#pragma unroll
            for (int r = 0; r < 4; r++) sr[r] = __shfl(scale, 4 * g + r);
#pragma unroll
            for (int i = 0; i < 16; i++) {
                f32x4 o = Of[i];
                o[0] *= sr[0]; o[1] *= sr[1]; o[2] *= sr[2]; o[3] *= sr[3];
                Of[i] = o;
            }
        }

        // --- P -> A-fragment via per-wave LDS (keys contiguous per row q) ---
        f16x4 w0, w1;
        w0.x = (_Float16)p0[0]; w0.y = (_Float16)p0[1]; w0.z = (_Float16)p0[2]; w0.w = (_Float16)p0[3];
        w1.x = (_Float16)p1[0]; w1.y = (_Float16)p1[1]; w1.z = (_Float16)p1[2]; w1.w = (_Float16)p1[3];
        *(f16x4*)(pw + lr * 36 + 4 * g) = w0;        // keys 4g..4g+3
        *(f16x4*)(pw + lr * 36 + 16 + 4 * g) = w1;   // keys 16+4g..16+4g+3
        asm volatile("s_waitcnt lgkmcnt(0)" ::: "memory");
        const f16x4 a0 = *(const f16x4*)(pw + lr * 36 + 8 * g);
        const f16x4 a1 = *(const f16x4*)(pw + lr * 36 + 8 * g + 4);
        f16x8 pf;
        pf[0] = a0.x; pf[1] = a0.y; pf[2] = a0.z; pf[3] = a0.w;
        pf[4] = a1.x; pf[5] = a1.y; pf[6] = a1.z; pf[7] = a1.w;

        // --- PV: B-frag = V[key = kt+8g+j][d = dc*16+lr], contiguous in vt ---
        const _Float16* vp = vbase + kt + 8 * g;
#pragma unroll
        for (int dc = 0; dc < 16; dc++) {
            const f16x8 vf = *(const f16x8*)(vp + (size_t)(dc * 16 + lr) * 4096);
            Of[dc] = __builtin_amdgcn_mfma_f32_16x16x32_f16(pf, vf, Of[dc], 0, 0, 0);
        }
    }

    // --- epilogue: O rows are q = qs + 4g + r; lsum lives at lane lr = that row
    const float linv = __builtin_amdgcn_rcpf(lsum);
    float lr4[4];
#pragma unroll
    for (int r = 0; r < 4; r++) lr4[r] = __shfl(linv, 4 * g + r);
#pragma unroll
    for (int dc = 0; dc < 16; dc++)
#pragma unroll
        for (int r = 0; r < 4; r++) {
            const size_t srow = qs + 4 * g + r;
            attnout[srow * 2048 + h * 256 + dc * 16 + lr] = (_Float16)(Of[dc][r] * lr4[r]);
        }
}

// ---------------------------------------------------------------------------
extern "C" void kernel_launch(void* const* d_in, const int* in_sizes, int n_in,
                              void* d_out, int out_size, void* d_ws, size_t ws_size,
                              hipStream_t stream) {
    (void)in_sizes; (void)n_in; (void)out_size; (void)ws_size;
    const float* hidden  = (const float*)d_in[0];
    const float* Wq      = (const float*)d_in[1];
    const float* Wk      = (const float*)d_in[2];
    const float* Wv      = (const float*)d_in[3];
    const float* Wo      = (const float*)d_in[4];
    const float* q_scale = (const float*)d_in[5];
    const float* k_scale = (const float*)d_in[6];

    char* ws = (char*)d_ws;
    size_t off = 0;
    auto carve = [&](size_t bytes) -> char* {
        char* p = ws + off;
        off += (bytes + 255) & ~(size_t)255;
        return p;
    };
    _Float16* Hh    = (_Float16*)carve((size_t)4096 * 2048 * 2);
    // WqT/WkT/WvT carved contiguously -> one [4096][2048] f16 B^T for fused QKV
    _Float16* WqT   = (_Float16*)carve((size_t)2048 * 2048 * 2);
    _Float16* WkT   = (_Float16*)carve((size_t)1024 * 2048 * 2);
    _Float16* WvT   = (_Float16*)carve((size_t)1024 * 2048 * 2);
    _Float16* WoT   = (_Float16*)carve((size_t)2048 * 2048 * 2);
    float*    qkvf  = (float*)carve((size_t)4096 * 4096 * 4);  // fused C
    _Float16* qn    = (_Float16*)carve((size_t)8 * 4096 * 256 * 2);
    _Float16* kn    = (_Float16*)carve((size_t)4 * 4096 * 256 * 2);
    _Float16* vt    = (_Float16*)carve((size_t)4 * 256 * 4096 * 2);  // [kvh][d][s]
    _Float16* attnb = (_Float16*)carve((size_t)4096 * 2048 * 2);
    float*    ct    = (float*)carve((size_t)4096 * 128 * 4);
    float*    stb   = (float*)carve((size_t)4096 * 128 * 4);

    rope_tab<<<dim3(4096), dim3(128), 0, stream>>>(ct, stb);
    conv16<<<dim3(8192), dim3(256), 0, stream>>>(hidden, Hh);
    tconv<<<dim3(64, 64), dim3(32, 8), 0, stream>>>(Wq, WqT, 2048, 2048);
    tconv<<<dim3(32, 64), dim3(32, 8), 0, stream>>>(Wk, WkT, 2048, 1024);
    tconv<<<dim3(32, 64), dim3(32, 8), 0, stream>>>(Wv, WvT, 2048, 1024);
    tconv<<<dim3(64, 64), dim3(32, 8), 0, stream>>>(Wo, WoT, 2048, 2048);

    // fused QKV projection: [4096,2048] @ [2048,4096] -> qkvf
    gemm_f16<<<dim3(32, 32), dim3(256), 0, stream>>>(Hh, WqT, qkvf, 4096, 4096, 2048);

    norm_rope<<<dim3(8192), dim3(256), 0, stream>>>(qkvf, 0,    3, q_scale, ct, stb, qn);
    norm_rope<<<dim3(4096), dim3(256), 0, stream>>>(qkvf, 2048, 2, k_scale, ct, stb, kn);
    norm_v_t <<<dim3(128, 4), dim3(256), 0, stream>>>(qkvf, vt);

    attn_fwd<<<dim3(64, 8), dim3(256), 0, stream>>>(qn, kn, vt, attnb);

    gemm_f16<<<dim3(16, 32), dim3(256), 0, stream>>>(attnb, WoT, (float*)d_out, 4096, 2048, 2048);
}

// Round 4
// 556.742 us; speedup vs baseline: 1.0778x; 1.0778x over previous
//
#include <hip/hip_runtime.h>

#define KMASK (-2.3819763e38f)

typedef __attribute__((ext_vector_type(8))) _Float16 f16x8;
typedef __attribute__((ext_vector_type(4))) _Float16 f16x4;
typedef __attribute__((ext_vector_type(4))) float f32x4;

// async global->LDS, 16B per lane. LDS dest must be wave-uniform base (+lane*16 implicit).
__device__ __forceinline__ void gload_lds16(const void* g, void* lds) {
    __builtin_amdgcn_global_load_lds(
        (__attribute__((address_space(1))) void*)(g),
        (__attribute__((address_space(3))) void*)(lds), 16, 0, 0);
}

// 50 * tanh(x / 50), fast: tanh(a) = (1 - e^{-2a}) / (1 + e^{-2a}), sign-restored.
__device__ __forceinline__ float softcap50(float x) {
    const float t = __expf(-0.04f * fabsf(x));
    const float r = (1.f - t) * __builtin_amdgcn_rcpf(1.f + t);
    return copysignf(50.f * r, x);
}

// ---------------------------------------------------------------------------
// RoPE table: ct/st[s][f] = cos/sin(s * theta^(-2f/256)), f in [0,128)
// ---------------------------------------------------------------------------
__global__ void rope_tab(float* __restrict__ ct, float* __restrict__ st) {
    const int s = blockIdx.x, f = threadIdx.x;
    const float inv = powf(10000.f, -2.f * (float)f / 256.f);
    const float a = (float)s * inv;
    ct[s * 128 + f] = cosf(a);
    st[s * 128 + f] = sinf(a);
}

// ---------------------------------------------------------------------------
// f32 -> f16 elementwise (4/thread)
// ---------------------------------------------------------------------------
__global__ void conv16(const float* __restrict__ x, _Float16* __restrict__ y) {
    const size_t i = ((size_t)blockIdx.x * 256 + threadIdx.x) * 4;
    const float4 v = *(const float4*)(x + i);
    f16x4 o;
    o.x = (_Float16)v.x; o.y = (_Float16)v.y; o.z = (_Float16)v.z; o.w = (_Float16)v.w;
    *(f16x4*)(y + i) = o;
}

// ---------------------------------------------------------------------------
// Tiled transpose + convert: W[K][N] f32 -> WT[N][K] f16
// ---------------------------------------------------------------------------
__global__ void tconv(const float* __restrict__ W, _Float16* __restrict__ WT, int K, int N) {
    __shared__ float t[32][33];
    const int n0 = blockIdx.x * 32, k0 = blockIdx.y * 32;
    const int tx = threadIdx.x, ty = threadIdx.y;
#pragma unroll
    for (int i = ty; i < 32; i += 8) t[i][tx] = W[(size_t)(k0 + i) * N + n0 + tx];
    __syncthreads();
#pragma unroll
    for (int i = ty; i < 32; i += 8) WT[(size_t)(n0 + i) * K + k0 + tx] = (_Float16)t[tx][i];
}

// ---------------------------------------------------------------------------
// GEMM: C[M][N] (OUT) = A[M][K] (f16, row-major) @ BT[N][K]^T (f16)
// 128x128 tile, BK=32, 4 waves (2x2), 16x16x32 MFMA, global_load_lds staging.
// Bijective XCD swizzle (nwg % 8 == 0 for all our grids).
// ---------------------------------------------------------------------------
template <typename OUT>
__global__ __launch_bounds__(256) void gemm_f16(
    const _Float16* __restrict__ A, const _Float16* __restrict__ BT,
    OUT* __restrict__ C, int M, int N, int K) {
    __shared__ _Float16 As[128 * 32];
    __shared__ _Float16 Bs[128 * 32];
    const int tid = threadIdx.x;
    const int l = tid & 63, w = tid >> 6;
    const int lr = l & 15, lg4 = l >> 4;
    const int wr = w >> 1, wc = w & 1;
    // XCD swizzle: contiguous chunk of block-space per XCD
    const int nwg = gridDim.x * gridDim.y;
    const int orig = blockIdx.x + gridDim.x * blockIdx.y;
    const int wg = (orig & 7) * (nwg >> 3) + (orig >> 3);
    const int bx = wg % gridDim.x, by = wg / gridDim.x;
    const size_t bm = (size_t)by * 128, bn = (size_t)bx * 128;

    f32x4 acc[4][4];
#pragma unroll
    for (int i = 0; i < 4; i++)
#pragma unroll
        for (int j = 0; j < 4; j++) acc[i][j] = (f32x4){0.f, 0.f, 0.f, 0.f};

    for (int k0 = 0; k0 < K; k0 += 32) {
#pragma unroll
        for (int i = 0; i < 2; i++) {
            const int o = w * 2048 + i * 1024 + l * 16;  // byte offset into 8KB tile
            const int row = o >> 6;                      // 64B per LDS row (32 f16)
            const int ce = (o & 63) >> 1;                // element within row
            gload_lds16(A + (bm + row) * (size_t)K + k0 + ce, (char*)As + (o - l * 16));
            gload_lds16(BT + (bn + row) * (size_t)K + k0 + ce, (char*)Bs + (o - l * 16));
        }
        asm volatile("s_waitcnt vmcnt(0)" ::: "memory");
        __syncthreads();

        f16x8 af[4], bfr[4];
#pragma unroll
        for (int mm = 0; mm < 4; mm++)
            af[mm] = *(const f16x8*)(As + (wr * 64 + mm * 16 + lr) * 32 + lg4 * 8);
#pragma unroll
        for (int nn = 0; nn < 4; nn++)
            bfr[nn] = *(const f16x8*)(Bs + (wc * 64 + nn * 16 + lr) * 32 + lg4 * 8);
#pragma unroll
        for (int mm = 0; mm < 4; mm++)
#pragma unroll
            for (int nn = 0; nn < 4; nn++)
                acc[mm][nn] = __builtin_amdgcn_mfma_f32_16x16x32_f16(af[mm], bfr[nn], acc[mm][nn], 0, 0, 0);
        __syncthreads();
    }
#pragma unroll
    for (int mm = 0; mm < 4; mm++)
#pragma unroll
        for (int nn = 0; nn < 4; nn++)
#pragma unroll
            for (int r = 0; r < 4; r++) {
                const size_t rr = bm + wr * 64 + mm * 16 + lg4 * 4 + r;
                const size_t cc = bn + wc * 64 + nn * 16 + lr;
                C[rr * N + cc] = (OUT)acc[mm][nn][r];
            }
}

// ---------------------------------------------------------------------------
// RMSNorm * (1+scale) + RoPE for q/k, reading from fused QKV f16 buffer.
// x row = qkv[s][colbase + h*256 + :256]. out layout: [h][s][256] f16.
// ---------------------------------------------------------------------------
__global__ __launch_bounds__(256) void norm_rope(
    const _Float16* __restrict__ x, int colbase, int logh,
    const float* __restrict__ scale,
    const float* __restrict__ ct, const float* __restrict__ st,
    _Float16* __restrict__ out) {
    const int w = threadIdx.x >> 6, l = threadIdx.x & 63;
    const int row = blockIdx.x * 4 + w;
    const int s = row >> logh, h = row & ((1 << logh) - 1);
    const f16x4 v4 = *(const f16x4*)(x + (size_t)s * 4096 + colbase + h * 256 + l * 4);
    const float vx = (float)v4.x, vy = (float)v4.y, vz = (float)v4.z, vw = (float)v4.w;
    float ss = vx * vx + vy * vy + vz * vz + vw * vw;
#pragma unroll
    for (int mm = 1; mm < 64; mm <<= 1) ss += __shfl_xor(ss, mm);
    const float r = rsqrtf(ss * (1.f / 256.f) + 1e-6f);
    const float4 sc = *(const float4*)(scale + l * 4);
    float y0 = vx * r * (1.f + sc.x), y1 = vy * r * (1.f + sc.y);
    float y2 = vz * r * (1.f + sc.z), y3 = vw * r * (1.f + sc.w);
    // RoPE
    const float p0 = __shfl_xor(y0, 32), p1 = __shfl_xor(y1, 32);
    const float p2 = __shfl_xor(y2, 32), p3 = __shfl_xor(y3, 32);
    const int f = (l & 31) * 4;
    const float4 c = *(const float4*)(ct + (size_t)s * 128 + f);
    const float4 sn = *(const float4*)(st + (size_t)s * 128 + f);
    if (l < 32) {
        y0 = y0 * c.x - p0 * sn.x; y1 = y1 * c.y - p1 * sn.y;
        y2 = y2 * c.z - p2 * sn.z; y3 = y3 * c.w - p3 * sn.w;
    } else {
        y0 = y0 * c.x + p0 * sn.x; y1 = y1 * c.y + p1 * sn.y;
        y2 = y2 * c.z + p2 * sn.z; y3 = y3 * c.w + p3 * sn.w;
    }
    f16x4 o;
    o.x = (_Float16)y0; o.y = (_Float16)y1; o.z = (_Float16)y2; o.w = (_Float16)y3;
    *(f16x4*)(out + ((size_t)h * 4096 + s) * 256 + l * 4) = o;
}

// ---------------------------------------------------------------------------
// V: RMSNorm (no weight) + transpose into TILED layout:
// vt[kvh][tile = s/32][d = 0..255][k = s%32] f16  (each 32-key tile's V^T is
// one contiguous 16KB block -> PV fragment loads are full-cache-line).
// Block: 32 s-rows of one kv head; 4 waves, 8 rows each; LDS tile transpose.
// ---------------------------------------------------------------------------
__global__ __launch_bounds__(256) void norm_v_t(
    const _Float16* __restrict__ x, _Float16* __restrict__ vt) {
    __shared__ _Float16 T[32][256];
    const int tid = threadIdx.x, l = tid & 63, w = tid >> 6;
    const int kvh = blockIdx.y;
    const int tile = blockIdx.x;  // s0 = tile*32
#pragma unroll
    for (int i = 0; i < 8; i++) {
        const int sr = w * 8 + i;
        const f16x4 v4 = *(const f16x4*)(x + (size_t)(tile * 32 + sr) * 4096 + 3072 + kvh * 256 + l * 4);
        const float vx = (float)v4.x, vy = (float)v4.y, vz = (float)v4.z, vw = (float)v4.w;
        float ss = vx * vx + vy * vy + vz * vz + vw * vw;
#pragma unroll
        for (int mm = 1; mm < 64; mm <<= 1) ss += __shfl_xor(ss, mm);
        const float r = rsqrtf(ss * (1.f / 256.f) + 1e-6f);
        f16x4 o;
        o.x = (_Float16)(vx * r); o.y = (_Float16)(vy * r);
        o.z = (_Float16)(vz * r); o.w = (_Float16)(vw * r);
        *(f16x4*)(&T[sr][l * 4]) = o;
    }
    __syncthreads();
    const int d = tid;  // 0..255
#pragma unroll
    for (int u = 0; u < 4; u++) {
        f16x8 b;
#pragma unroll
        for (int e = 0; e < 8; e++) b[e] = T[u * 8 + e][d];
        *(f16x8*)(vt + (((size_t)kvh * 128 + tile) * 256 + d) * 32 + u * 8) = b;
    }
}

// ---------------------------------------------------------------------------
// Flash attention, swapped-QK^T, software-pipelined. GQA (NH=8, NKV=4),
// window 1024, softcap 50. Grid (64, 8) -> XCD-swizzled so each XCD owns one
// head (its K/V stays in that XCD's L2). Block 256 = 4 independent waves
// (no barriers), wave w owns q rows qblk*64 + w*16 .. +15.
// q/k head-major f16 [h][s][256]; V tiled f16 [kvh][s/32][256][32].
// Pipeline per tile: issue V.a loads -> QK^T -> issue V.b + next K loads ->
// softmax -> P relayout -> PV.
// ---------------------------------------------------------------------------
__global__ __launch_bounds__(256, 2) void attn_fwd(
    const _Float16* __restrict__ qn, const _Float16* __restrict__ kn,
    const _Float16* __restrict__ vt, _Float16* __restrict__ attnout) {
    __shared__ _Float16 Parr[4][16 * 36];  // per-wave P buffer, stride 36 (pad)
    const int tid = threadIdx.x, l = tid & 63, w = tid >> 6;
    const int lr = l & 15, g = l >> 4;
    // XCD swizzle: 512 blocks, 8 XCDs -> 64 consecutive work-items per XCD
    // (= all 64 q-tiles of one head).
    const int orig = blockIdx.x + (blockIdx.y << 6);
    const int wg = (orig & 7) * 64 + (orig >> 3);
    const int h = wg >> 6, kvh = h >> 1;
    const int qs = (wg & 63) * 64 + w * 16;  // this wave's q-row start
    const int q = qs + lr;                   // this lane's softmax row

    // Q fragments (B-operand): lane holds Q[q][d = c*32 + g*8 + j]
    f16x8 qfr[8];
    {
        const _Float16* qp = qn + ((size_t)h * 4096 + qs + lr) * 256 + g * 8;
#pragma unroll
        for (int c = 0; c < 8; c++) qfr[c] = *(const f16x8*)(qp + c * 32);
    }
    f32x4 Of[16];
#pragma unroll
    for (int i = 0; i < 16; i++) Of[i] = (f32x4){0.f, 0.f, 0.f, 0.f};
    float m = KMASK, lsum = 0.f;

    const int kt0 = (qs >= 1024) ? ((qs - 1023) & ~31) : 0;
    const int ktend = qs + 16;
    _Float16* pw = &Parr[w][0];

    f16x8 kreg[16];
#define LOADK(KT)                                                                   \
    do {                                                                            \
        const _Float16* kp = kn + ((size_t)kvh * 4096 + (KT) + lr) * 256 + g * 8;   \
        _Pragma("unroll") for (int c = 0; c < 8; c++) {                             \
            kreg[c] = *(const f16x8*)(kp + c * 32);                                 \
            kreg[8 + c] = *(const f16x8*)(kp + 4096 + c * 32);                      \
        }                                                                           \
    } while (0)

    LOADK(kt0);
    for (int kt = kt0; kt < ktend; kt += 32) {
        // --- issue first half of V tile loads (consumed in PV, ~400cy away)
        const _Float16* vp = vt + (size_t)kvh * 1048576 + (size_t)(kt >> 5) * 8192 + lr * 32 + 8 * g;
        f16x8 vfa[8], vfb[8];
#pragma unroll
        for (int dc = 0; dc < 8; dc++) vfa[dc] = *(const f16x8*)(vp + dc * 512);

        // --- QK^T (swapped): lgf0 keys kt+4g+r, lgf1 keys kt+16+4g+r, col q
        f32x4 lgf0 = (f32x4){0.f, 0.f, 0.f, 0.f};
        f32x4 lgf1 = (f32x4){0.f, 0.f, 0.f, 0.f};
#pragma unroll
        for (int c = 0; c < 8; c++) {
            lgf0 = __builtin_amdgcn_mfma_f32_16x16x32_f16(kreg[c], qfr[c], lgf0, 0, 0, 0);
            lgf1 = __builtin_amdgcn_mfma_f32_16x16x32_f16(kreg[8 + c], qfr[c], lgf1, 0, 0, 0);
        }

        // --- issue second half of V + next tile's K (single-buffered kreg;
        //     loads are program-ordered after the MFMAs that read kreg)
#pragma unroll
        for (int dc = 0; dc < 8; dc++) vfb[dc] = *(const f16x8*)(vp + (8 + dc) * 512);
        {
            const int ktn = (kt + 32 < ktend) ? kt + 32 : kt;
            LOADK(ktn);
        }

        // --- softcap + mask (per-lane, row q) ---
        float c0[4], c1[4];
#pragma unroll
        for (int r = 0; r < 4; r++) {
            const int key0 = kt + 4 * g + r, key1 = key0 + 16;
            const float t0 = softcap50(lgf0[r]);
            const float t1 = softcap50(lgf1[r]);
            c0[r] = (key0 <= q && q - key0 < 1024) ? t0 : KMASK;
            c1[r] = (key1 <= q && q - key1 < 1024) ? t1 : KMASK;
        }
        float mx = fmaxf(fmaxf(fmaxf(c0[0], c0[1]), fmaxf(c0[2], c0[3])),
                         fmaxf(fmaxf(c1[0], c1[1]), fmaxf(c1[2], c1[3])));
        mx = fmaxf(mx, __shfl_xor(mx, 16));
        mx = fmaxf(mx, __shfl_xor(mx, 32));
        // T13 defer-max: only rescale when max grows by > 8
        const bool need = mx > m + 8.f;
        float scale = 1.f;
        if (need) { scale = __expf(m - mx); m = mx; }
        float p0[4], p1[4];
        float ps = 0.f;
#pragma unroll
        for (int r = 0; r < 4; r++) {
            p0[r] = __expf(c0[r] - m);
            p1[r] = __expf(c1[r] - m);
            ps += p0[r] + p1[r];
        }
        ps += __shfl_xor(ps, 16);
        ps += __shfl_xor(ps, 32);
        lsum = lsum * scale + ps;
        if (__any(need)) {
            float sr[4];
#pragma unroll
            for (int r = 0; r < 4; r++) sr[r] = __shfl(scale, 4 * g + r);
#pragma unroll
            for (int i = 0; i < 16; i++) {
                f32x4 o = Of[i];
                o[0] *= sr[0]; o[1] *= sr[1]; o[2] *= sr[2]; o[3] *= sr[3];
                Of[i] = o;
            }
        }

        // --- P -> A-fragment via per-wave LDS ---
        f16x4 w0, w1;
        w0.x = (_Float16)p0[0]; w0.y = (_Float16)p0[1]; w0.z = (_Float16)p0[2]; w0.w = (_Float16)p0[3];
        w1.x = (_Float16)p1[0]; w1.y = (_Float16)p1[1]; w1.z = (_Float16)p1[2]; w1.w = (_Float16)p1[3];
        *(f16x4*)(pw + lr * 36 + 4 * g) = w0;
        *(f16x4*)(pw + lr * 36 + 16 + 4 * g) = w1;
        asm volatile("s_waitcnt lgkmcnt(0)" ::: "memory");
        const f16x4 a0 = *(const f16x4*)(pw + lr * 36 + 8 * g);
        const f16x4 a1 = *(const f16x4*)(pw + lr * 36 + 8 * g + 4);
        f16x8 pf;
        pf[0] = a0.x; pf[1] = a0.y; pf[2] = a0.z; pf[3] = a0.w;
        pf[4] = a1.x; pf[5] = a1.y; pf[6] = a1.z; pf[7] = a1.w;

        // --- PV ---
#pragma unroll
        for (int dc = 0; dc < 8; dc++)
            Of[dc] = __builtin_amdgcn_mfma_f32_16x16x32_f16(pf, vfa[dc], Of[dc], 0, 0, 0);
#pragma unroll
        for (int dc = 0; dc < 8; dc++)
            Of[8 + dc] = __builtin_amdgcn_mfma_f32_16x16x32_f16(pf, vfb[dc], Of[8 + dc], 0, 0, 0);
    }
#undef LOADK

    // --- epilogue: O rows are q = qs + 4g + r; lsum lives at lane lr = row
    const float linv = __builtin_amdgcn_rcpf(lsum);
    float lr4[4];
#pragma unroll
    for (int r = 0; r < 4; r++) lr4[r] = __shfl(linv, 4 * g + r);
#pragma unroll
    for (int dc = 0; dc < 16; dc++)
#pragma unroll
        for (int r = 0; r < 4; r++) {
            const size_t srow = qs + 4 * g + r;
            attnout[srow * 2048 + h * 256 + dc * 16 + lr] = (_Float16)(Of[dc][r] * lr4[r]);
        }
}

// ---------------------------------------------------------------------------
extern "C" void kernel_launch(void* const* d_in, const int* in_sizes, int n_in,
                              void* d_out, int out_size, void* d_ws, size_t ws_size,
                              hipStream_t stream) {
    (void)in_sizes; (void)n_in; (void)out_size; (void)ws_size;
    const float* hidden  = (const float*)d_in[0];
    const float* Wq      = (const float*)d_in[1];
    const float* Wk      = (const float*)d_in[2];
    const float* Wv      = (const float*)d_in[3];
    const float* Wo      = (const float*)d_in[4];
    const float* q_scale = (const float*)d_in[5];
    const float* k_scale = (const float*)d_in[6];

    char* ws = (char*)d_ws;
    size_t off = 0;
    auto carve = [&](size_t bytes) -> char* {
        char* p = ws + off;
        off += (bytes + 255) & ~(size_t)255;
        return p;
    };
    _Float16* Hh    = (_Float16*)carve((size_t)4096 * 2048 * 2);
    // WqT/WkT/WvT contiguous -> one [4096][2048] f16 B^T for fused QKV
    _Float16* WqT   = (_Float16*)carve((size_t)2048 * 2048 * 2);
    _Float16* WkT   = (_Float16*)carve((size_t)1024 * 2048 * 2);
    _Float16* WvT   = (_Float16*)carve((size_t)1024 * 2048 * 2);
    _Float16* WoT   = (_Float16*)carve((size_t)2048 * 2048 * 2);
    _Float16* qkvf  = (_Float16*)carve((size_t)4096 * 4096 * 2);  // fused C (f16)
    _Float16* qn    = (_Float16*)carve((size_t)8 * 4096 * 256 * 2);
    _Float16* kn    = (_Float16*)carve((size_t)4 * 4096 * 256 * 2);
    _Float16* vt    = (_Float16*)carve((size_t)4 * 128 * 256 * 32 * 2);  // tiled V^T
    _Float16* attnb = (_Float16*)carve((size_t)4096 * 2048 * 2);
    float*    ct    = (float*)carve((size_t)4096 * 128 * 4);
    float*    stb   = (float*)carve((size_t)4096 * 128 * 4);

    rope_tab<<<dim3(4096), dim3(128), 0, stream>>>(ct, stb);
    conv16<<<dim3(8192), dim3(256), 0, stream>>>(hidden, Hh);
    tconv<<<dim3(64, 64), dim3(32, 8), 0, stream>>>(Wq, WqT, 2048, 2048);
    tconv<<<dim3(32, 64), dim3(32, 8), 0, stream>>>(Wk, WkT, 2048, 1024);
    tconv<<<dim3(32, 64), dim3(32, 8), 0, stream>>>(Wv, WvT, 2048, 1024);
    tconv<<<dim3(64, 64), dim3(32, 8), 0, stream>>>(Wo, WoT, 2048, 2048);

    // fused QKV projection: [4096,2048] @ [2048,4096] -> qkvf (f16)
    gemm_f16<_Float16><<<dim3(32, 32), dim3(256), 0, stream>>>(Hh, WqT, qkvf, 4096, 4096, 2048);

    norm_rope<<<dim3(8192), dim3(256), 0, stream>>>(qkvf, 0,    3, q_scale, ct, stb, qn);
    norm_rope<<<dim3(4096), dim3(256), 0, stream>>>(qkvf, 2048, 2, k_scale, ct, stb, kn);
    norm_v_t <<<dim3(128, 4), dim3(256), 0, stream>>>(qkvf, vt);

    attn_fwd<<<dim3(64, 8), dim3(256), 0, stream>>>(qn, kn, vt, attnb);

    gemm_f16<float><<<dim3(16, 32), dim3(256), 0, stream>>>(attnb, WoT, (float*)d_out, 4096, 2048, 2048);
}

// Round 11
// 440.655 us; speedup vs baseline: 1.3617x; 1.2634x over previous
//
#include <hip/hip_runtime.h>

#define KMASK (-2.3819763e38f)

typedef __attribute__((ext_vector_type(8))) _Float16 f16x8;
typedef __attribute__((ext_vector_type(4))) _Float16 f16x4;
typedef __attribute__((ext_vector_type(4))) float f32x4;

// async global->LDS, 16B per lane. LDS dest must be wave-uniform base (+lane*16 implicit).
__device__ __forceinline__ void gload_lds16(const void* g, void* lds) {
    __builtin_amdgcn_global_load_lds(
        (__attribute__((address_space(1))) void*)(g),
        (__attribute__((address_space(3))) void*)(lds), 16, 0, 0);
}

// 50 * tanh(x / 50), fast: tanh(a) = (1 - e^{-2a}) / (1 + e^{-2a}), sign-restored.
__device__ __forceinline__ float softcap50(float x) {
    const float t = __expf(-0.04f * fabsf(x));
    const float r = (1.f - t) * __builtin_amdgcn_rcpf(1.f + t);
    return copysignf(50.f * r, x);
}

// ---------------------------------------------------------------------------
// RoPE table: ct/st[s][f] = cos/sin(s * theta^(-2f/256)), f in [0,128)
// ---------------------------------------------------------------------------
__global__ void rope_tab(float* __restrict__ ct, float* __restrict__ st) {
    const int s = blockIdx.x, f = threadIdx.x;
    const float inv = powf(10000.f, -2.f * (float)f / 256.f);
    const float a = (float)s * inv;
    ct[s * 128 + f] = cosf(a);
    st[s * 128 + f] = sinf(a);
}

// ---------------------------------------------------------------------------
// f32 -> f16 elementwise (4/thread)
// ---------------------------------------------------------------------------
__global__ void conv16(const float* __restrict__ x, _Float16* __restrict__ y) {
    const size_t i = ((size_t)blockIdx.x * 256 + threadIdx.x) * 4;
    const float4 v = *(const float4*)(x + i);
    f16x4 o;
    o.x = (_Float16)v.x; o.y = (_Float16)v.y; o.z = (_Float16)v.z; o.w = (_Float16)v.w;
    *(f16x4*)(y + i) = o;
}

// ---------------------------------------------------------------------------
// Tiled transpose + convert: W[K][N] f32 -> WT[N][K] f16
// ---------------------------------------------------------------------------
__global__ void tconv(const float* __restrict__ W, _Float16* __restrict__ WT, int K, int N) {
    __shared__ float t[32][33];
    const int n0 = blockIdx.x * 32, k0 = blockIdx.y * 32;
    const int tx = threadIdx.x, ty = threadIdx.y;
#pragma unroll
    for (int i = ty; i < 32; i += 8) t[i][tx] = W[(size_t)(k0 + i) * N + n0 + tx];
    __syncthreads();
#pragma unroll
    for (int i = ty; i < 32; i += 8) WT[(size_t)(n0 + i) * K + k0 + tx] = (_Float16)t[tx][i];
}

// ---------------------------------------------------------------------------
// GEMM: C[M][N] (OUT) = A[M][K] (f16, row-major) @ BT[N][K]^T (f16)
// 128x128 tile, BK=32, 4 waves (2x2), 16x16x32 MFMA, global_load_lds staging.
// Bijective XCD swizzle (nwg % 8 == 0 for all our grids).
// ---------------------------------------------------------------------------
template <typename OUT>
__global__ __launch_bounds__(256) void gemm_f16(
    const _Float16* __restrict__ A, const _Float16* __restrict__ BT,
    OUT* __restrict__ C, int M, int N, int K) {
    __shared__ _Float16 As[128 * 32];
    __shared__ _Float16 Bs[128 * 32];
    const int tid = threadIdx.x;
    const int l = tid & 63, w = tid >> 6;
    const int lr = l & 15, lg4 = l >> 4;
    const int wr = w >> 1, wc = w & 1;
    // XCD swizzle: contiguous chunk of block-space per XCD
    const int nwg = gridDim.x * gridDim.y;
    const int orig = blockIdx.x + gridDim.x * blockIdx.y;
    const int wg = (orig & 7) * (nwg >> 3) + (orig >> 3);
    const int bx = wg % gridDim.x, by = wg / gridDim.x;
    const size_t bm = (size_t)by * 128, bn = (size_t)bx * 128;

    f32x4 acc[4][4];
#pragma unroll
    for (int i = 0; i < 4; i++)
#pragma unroll
        for (int j = 0; j < 4; j++) acc[i][j] = (f32x4){0.f, 0.f, 0.f, 0.f};

    for (int k0 = 0; k0 < K; k0 += 32) {
#pragma unroll
        for (int i = 0; i < 2; i++) {
            const int o = w * 2048 + i * 1024 + l * 16;  // byte offset into 8KB tile
            const int row = o >> 6;                      // 64B per LDS row (32 f16)
            const int ce = (o & 63) >> 1;                // element within row
            gload_lds16(A + (bm + row) * (size_t)K + k0 + ce, (char*)As + (o - l * 16));
            gload_lds16(BT + (bn + row) * (size_t)K + k0 + ce, (char*)Bs + (o - l * 16));
        }
        asm volatile("s_waitcnt vmcnt(0)" ::: "memory");
        __syncthreads();

        f16x8 af[4], bfr[4];
#pragma unroll
        for (int mm = 0; mm < 4; mm++)
            af[mm] = *(const f16x8*)(As + (wr * 64 + mm * 16 + lr) * 32 + lg4 * 8);
#pragma unroll
        for (int nn = 0; nn < 4; nn++)
            bfr[nn] = *(const f16x8*)(Bs + (wc * 64 + nn * 16 + lr) * 32 + lg4 * 8);
#pragma unroll
        for (int mm = 0; mm < 4; mm++)
#pragma unroll
            for (int nn = 0; nn < 4; nn++)
                acc[mm][nn] = __builtin_amdgcn_mfma_f32_16x16x32_f16(af[mm], bfr[nn], acc[mm][nn], 0, 0, 0);
        __syncthreads();
    }
#pragma unroll
    for (int mm = 0; mm < 4; mm++)
#pragma unroll
        for (int nn = 0; nn < 4; nn++)
#pragma unroll
            for (int r = 0; r < 4; r++) {
                const size_t rr = bm + wr * 64 + mm * 16 + lg4 * 4 + r;
                const size_t cc = bn + wc * 64 + nn * 16 + lr;
                C[rr * N + cc] = (OUT)acc[mm][nn][r];
            }
}

// ---------------------------------------------------------------------------
// RMSNorm * (1+scale) + RoPE for q/k, reading from fused QKV f16 buffer.
// x row = qkv[s][colbase + h*256 + :256]. out layout: [h][s][256] f16.
// kswz=1 (K path): row elements stored XOR-swizzled (el ^= ((s&7)<<3)) so the
// attn kernel's linear global_load_lds staging lands bank-conflict-free K
// tiles in LDS (read side applies the same XOR).
// ---------------------------------------------------------------------------
__global__ __launch_bounds__(256) void norm_rope(
    const _Float16* __restrict__ x, int colbase, int logh, int kswz,
    const float* __restrict__ scale,
    const float* __restrict__ ct, const float* __restrict__ st,
    _Float16* __restrict__ out) {
    const int w = threadIdx.x >> 6, l = threadIdx.x & 63;
    const int row = blockIdx.x * 4 + w;
    const int s = row >> logh, h = row & ((1 << logh) - 1);
    const f16x4 v4 = *(const f16x4*)(x + (size_t)s * 4096 + colbase + h * 256 + l * 4);
    const float vx = (float)v4.x, vy = (float)v4.y, vz = (float)v4.z, vw = (float)v4.w;
    float ss = vx * vx + vy * vy + vz * vz + vw * vw;
#pragma unroll
    for (int mm = 1; mm < 64; mm <<= 1) ss += __shfl_xor(ss, mm);
    const float r = rsqrtf(ss * (1.f / 256.f) + 1e-6f);
    const float4 sc = *(const float4*)(scale + l * 4);
    float y0 = vx * r * (1.f + sc.x), y1 = vy * r * (1.f + sc.y);
    float y2 = vz * r * (1.f + sc.z), y3 = vw * r * (1.f + sc.w);
    // RoPE
    const float p0 = __shfl_xor(y0, 32), p1 = __shfl_xor(y1, 32);
    const float p2 = __shfl_xor(y2, 32), p3 = __shfl_xor(y3, 32);
    const int f = (l & 31) * 4;
    const float4 c = *(const float4*)(ct + (size_t)s * 128 + f);
    const float4 sn = *(const float4*)(st + (size_t)s * 128 + f);
    if (l < 32) {
        y0 = y0 * c.x - p0 * sn.x; y1 = y1 * c.y - p1 * sn.y;
        y2 = y2 * c.z - p2 * sn.z; y3 = y3 * c.w - p3 * sn.w;
    } else {
        y0 = y0 * c.x + p0 * sn.x; y1 = y1 * c.y + p1 * sn.y;
        y2 = y2 * c.z + p2 * sn.z; y3 = y3 * c.w + p3 * sn.w;
    }
    f16x4 o;
    o.x = (_Float16)y0; o.y = (_Float16)y1; o.z = (_Float16)y2; o.w = (_Float16)y3;
    const int col = kswz ? ((l * 4) ^ ((s & 7) << 3)) : (l * 4);
    *(f16x4*)(out + ((size_t)h * 4096 + s) * 256 + col) = o;
}

// ---------------------------------------------------------------------------
// V: RMSNorm (no weight) + transpose into TILED layout:
// vt[kvh][tile = s/32][d = 0..255][k = s%32] f16  (each 32-key tile's V^T is
// one contiguous 16KB block -> staging is a linear 16KB copy).
// ---------------------------------------------------------------------------
__global__ __launch_bounds__(256) void norm_v_t(
    const _Float16* __restrict__ x, _Float16* __restrict__ vt) {
    __shared__ _Float16 T[32][256];
    const int tid = threadIdx.x, l = tid & 63, w = tid >> 6;
    const int kvh = blockIdx.y;
    const int tile = blockIdx.x;  // s0 = tile*32
#pragma unroll
    for (int i = 0; i < 8; i++) {
        const int sr = w * 8 + i;
        const f16x4 v4 = *(const f16x4*)(x + (size_t)(tile * 32 + sr) * 4096 + 3072 + kvh * 256 + l * 4);
        const float vx = (float)v4.x, vy = (float)v4.y, vz = (float)v4.z, vw = (float)v4.w;
        float ss = vx * vx + vy * vy + vz * vz + vw * vw;
#pragma unroll
        for (int mm = 1; mm < 64; mm <<= 1) ss += __shfl_xor(ss, mm);
        const float r = rsqrtf(ss * (1.f / 256.f) + 1e-6f);
        f16x4 o;
        o.x = (_Float16)(vx * r); o.y = (_Float16)(vy * r);
        o.z = (_Float16)(vz * r); o.w = (_Float16)(vw * r);
        *(f16x4*)(&T[sr][l * 4]) = o;
    }
    __syncthreads();
    const int d = tid;  // 0..255
#pragma unroll
    for (int u = 0; u < 4; u++) {
        f16x8 b;
#pragma unroll
        for (int e = 0; e < 8; e++) b[e] = T[u * 8 + e][d];
        *(f16x8*)(vt + (((size_t)kvh * 128 + tile) * 256 + d) * 32 + u * 8) = b;
    }
}

// ---------------------------------------------------------------------------
// Flash attention, block-cooperative LDS-staged K/V (GEMM-style 2-phase).
// GQA (NH=8, NKV=4), window 1024, softcap 50. Grid (64,8) XCD-swizzled
// (each XCD owns one head). Block 256 = 4 waves sharing one kt loop over the
// block's union window; per-wave skip for dead tiles; per-lane masking.
// Schedule per tile: STAGE(next, global_load_lds) -> compute(cur) ->
// vmcnt(0) -> barrier.  K LDS rows XOR-swizzled (source pre-swizzled).
// ---------------------------------------------------------------------------
__global__ __launch_bounds__(256, 2) void attn_fwd(
    const _Float16* __restrict__ qn, const _Float16* __restrict__ kn,
    const _Float16* __restrict__ vt, _Float16* __restrict__ attnout) {
    __shared__ _Float16 Ks[2][32 * 256];   // [key][d], rows byte^((key&7)<<4)
    __shared__ _Float16 Vs[2][256 * 32];   // [d][k]
    __shared__ _Float16 Parr[4][16 * 36];  // per-wave P relayout buffer
    const int tid = threadIdx.x, l = tid & 63, w = tid >> 6;
    const int lr = l & 15, g = l >> 4;
    // XCD swizzle: 512 blocks, 8 XCDs -> 64 consecutive wg per XCD (one head).
    const int orig = blockIdx.x + (blockIdx.y << 6);
    const int wg = (orig & 7) * 64 + (orig >> 3);
    const int h = wg >> 6, kvh = h >> 1;
    const int qs_b = (wg & 63) * 64;          // block's q-row start
    const int qs = qs_b + w * 16;             // this wave's q-row start
    const int q = qs + lr;                    // this lane's softmax row

    // Q fragments (B-operand): lane holds Q[q][d = c*32 + g*8 + j]
    f16x8 qfr[8];
    {
        const _Float16* qp = qn + ((size_t)h * 4096 + qs + lr) * 256 + g * 8;
#pragma unroll
        for (int c = 0; c < 8; c++) qfr[c] = *(const f16x8*)(qp + c * 32);
    }
    f32x4 Of[16];
#pragma unroll
    for (int i = 0; i < 16; i++) Of[i] = (f32x4){0.f, 0.f, 0.f, 0.f};
    // m init: finite very-negative (NOT KMASK) so all-masked tiles keep
    // exp(KMASK - m) == 0 instead of exp(0) == 1.
    float m = -1e30f, lsum = 0.f;

    const int kt_lo = (qs_b >= 1024) ? ((qs_b - 1023) & ~31) : 0;
    const int NT = (qs_b + 64 - kt_lo) >> 5;  // union window tiles (<= 34)
    const char* kbase = (const char*)(kn + (size_t)kvh * 4096 * 256);
    const char* vbase = (const char*)(vt + (size_t)kvh * 128 * 8192);
    _Float16* pw = &Parr[w][0];
    const int kx = (lr & 7) << 4;

#define STAGE(B, KT)                                                          \
    do {                                                                      \
        const char* ksrc = kbase + (size_t)(KT) * 512;                        \
        const char* vsrc = vbase + (size_t)((KT) >> 5) * 16384;               \
        _Pragma("unroll") for (int it = 0; it < 4; ++it) {                    \
            const int o = it * 4096 + w * 1024; /* wave-uniform byte base */  \
            gload_lds16(ksrc + o + l * 16, (char*)&Ks[(B)][0] + o);           \
            gload_lds16(vsrc + o + l * 16, (char*)&Vs[(B)][0] + o);           \
        }                                                                     \
    } while (0)

    STAGE(0, kt_lo);
    asm volatile("s_waitcnt vmcnt(0)" ::: "memory");
    __syncthreads();

    for (int t = 0; t < NT; ++t) {
        const int kt = kt_lo + (t << 5);
        const int b = t & 1;
        if (t + 1 < NT) STAGE(b ^ 1, kt + 32);

        // wave-uniform dead-tile skip (tile fully outside this wave's window)
        const bool skip = (kt + 31 < qs - 1023) || (kt > qs + 15);
        if (!skip) {
            // --- QK^T (swapped): lane (lr,g) gets S[key=kt(+16)+4g+r][q]
            f32x4 lgf0 = (f32x4){0.f, 0.f, 0.f, 0.f};
            f32x4 lgf1 = (f32x4){0.f, 0.f, 0.f, 0.f};
            const char* kb = (const char*)&Ks[b][0] + lr * 512;
#pragma unroll
            for (int c = 0; c < 8; c++) {
                const int off = (g * 16 + c * 64) ^ kx;  // match source swizzle
                const f16x8 k0 = *(const f16x8*)(kb + off);
                const f16x8 k1 = *(const f16x8*)(kb + 8192 + off);
                lgf0 = __builtin_amdgcn_mfma_f32_16x16x32_f16(k0, qfr[c], lgf0, 0, 0, 0);
                lgf1 = __builtin_amdgcn_mfma_f32_16x16x32_f16(k1, qfr[c], lgf1, 0, 0, 0);
            }

            // --- softcap + mask (per-lane, row q) ---
            float c0[4], c1[4];
#pragma unroll
            for (int r = 0; r < 4; r++) {
                const int key0 = kt + 4 * g + r, key1 = key0 + 16;
                const float t0 = softcap50(lgf0[r]);
                const float t1 = softcap50(lgf1[r]);
                c0[r] = (key0 <= q && q - key0 < 1024) ? t0 : KMASK;
                c1[r] = (key1 <= q && q - key1 < 1024) ? t1 : KMASK;
            }
            float mx = fmaxf(fmaxf(fmaxf(c0[0], c0[1]), fmaxf(c0[2], c0[3])),
                             fmaxf(fmaxf(c1[0], c1[1]), fmaxf(c1[2], c1[3])));
            mx = fmaxf(mx, __shfl_xor(mx, 16));
            mx = fmaxf(mx, __shfl_xor(mx, 32));
            // T13 defer-max
            const bool need = mx > m + 8.f;
            float scale = 1.f;
            if (need) { scale = __expf(m - mx); m = mx; }
            float p0[4], p1[4];
            float ps = 0.f;
#pragma unroll
            for (int r = 0; r < 4; r++) {
                p0[r] = __expf(c0[r] - m);
                p1[r] = __expf(c1[r] - m);
                ps += p0[r] + p1[r];
            }
            ps += __shfl_xor(ps, 16);
            ps += __shfl_xor(ps, 32);
            lsum = lsum * scale + ps;
            if (__any(need)) {
                float sr[4];
#pragma unroll
                for (int r = 0; r < 4; r++) sr[r] = __shfl(scale, 4 * g + r);
#pragma unroll
                for (int i = 0; i < 16; i++) {
                    f32x4 o = Of[i];
                    o[0] *= sr[0]; o[1] *= sr[1]; o[2] *= sr[2]; o[3] *= sr[3];
                    Of[i] = o;
                }
            }

            // --- P -> A-fragment via per-wave LDS ---
            f16x4 w0, w1;
            w0.x = (_Float16)p0[0]; w0.y = (_Float16)p0[1]; w0.z = (_Float16)p0[2]; w0.w = (_Float16)p0[3];
            w1.x = (_Float16)p1[0]; w1.y = (_Float16)p1[1]; w1.z = (_Float16)p1[2]; w1.w = (_Float16)p1[3];
            *(f16x4*)(pw + lr * 36 + 4 * g) = w0;
            *(f16x4*)(pw + lr * 36 + 16 + 4 * g) = w1;
            asm volatile("s_waitcnt lgkmcnt(0)" ::: "memory");
            const f16x4 a0 = *(const f16x4*)(pw + lr * 36 + 8 * g);
            const f16x4 a1 = *(const f16x4*)(pw + lr * 36 + 8 * g + 4);
            f16x8 pf;
            pf[0] = a0.x; pf[1] = a0.y; pf[2] = a0.z; pf[3] = a0.w;
            pf[4] = a1.x; pf[5] = a1.y; pf[6] = a1.z; pf[7] = a1.w;

            // --- PV: B-frag = Vs[d = dc*16+lr][k = 8g+j] ---
            const char* vb = (const char*)&Vs[b][0] + lr * 64 + g * 16;
#pragma unroll
            for (int dc = 0; dc < 16; dc++) {
                const f16x8 vf = *(const f16x8*)(vb + dc * 1024);
                Of[dc] = __builtin_amdgcn_mfma_f32_16x16x32_f16(pf, vf, Of[dc], 0, 0, 0);
            }
        }
        asm volatile("s_waitcnt vmcnt(0)" ::: "memory");
        __syncthreads();
    }
#undef STAGE

    // --- epilogue: O rows are q = qs + 4g + r; lsum lives at lane lr = row
    const float linv = __builtin_amdgcn_rcpf(lsum);
    float lr4[4];
#pragma unroll
    for (int r = 0; r < 4; r++) lr4[r] = __shfl(linv, 4 * g + r);
#pragma unroll
    for (int dc = 0; dc < 16; dc++)
#pragma unroll
        for (int r = 0; r < 4; r++) {
            const size_t srow = qs + 4 * g + r;
            attnout[srow * 2048 + h * 256 + dc * 16 + lr] = (_Float16)(Of[dc][r] * lr4[r]);
        }
}

// ---------------------------------------------------------------------------
extern "C" void kernel_launch(void* const* d_in, const int* in_sizes, int n_in,
                              void* d_out, int out_size, void* d_ws, size_t ws_size,
                              hipStream_t stream) {
    (void)in_sizes; (void)n_in; (void)out_size; (void)ws_size;
    const float* hidden  = (const float*)d_in[0];
    const float* Wq      = (const float*)d_in[1];
    const float* Wk      = (const float*)d_in[2];
    const float* Wv      = (const float*)d_in[3];
    const float* Wo      = (const float*)d_in[4];
    const float* q_scale = (const float*)d_in[5];
    const float* k_scale = (const float*)d_in[6];

    char* ws = (char*)d_ws;
    size_t off = 0;
    auto carve = [&](size_t bytes) -> char* {
        char* p = ws + off;
        off += (bytes + 255) & ~(size_t)255;
        return p;
    };
    _Float16* Hh    = (_Float16*)carve((size_t)4096 * 2048 * 2);
    // WqT/WkT/WvT contiguous -> one [4096][2048] f16 B^T for fused QKV
    _Float16* WqT   = (_Float16*)carve((size_t)2048 * 2048 * 2);
    _Float16* WkT   = (_Float16*)carve((size_t)1024 * 2048 * 2);
    _Float16* WvT   = (_Float16*)carve((size_t)1024 * 2048 * 2);
    _Float16* WoT   = (_Float16*)carve((size_t)2048 * 2048 * 2);
    _Float16* qkvf  = (_Float16*)carve((size_t)4096 * 4096 * 2);  // fused C (f16)
    _Float16* qn    = (_Float16*)carve((size_t)8 * 4096 * 256 * 2);
    _Float16* kn    = (_Float16*)carve((size_t)4 * 4096 * 256 * 2);
    _Float16* vt    = (_Float16*)carve((size_t)4 * 128 * 256 * 32 * 2);  // tiled V^T
    _Float16* attnb = (_Float16*)carve((size_t)4096 * 2048 * 2);
    float*    ct    = (float*)carve((size_t)4096 * 128 * 4);
    float*    stb   = (float*)carve((size_t)4096 * 128 * 4);

    rope_tab<<<dim3(4096), dim3(128), 0, stream>>>(ct, stb);
    conv16<<<dim3(8192), dim3(256), 0, stream>>>(hidden, Hh);
    tconv<<<dim3(64, 64), dim3(32, 8), 0, stream>>>(Wq, WqT, 2048, 2048);
    tconv<<<dim3(32, 64), dim3(32, 8), 0, stream>>>(Wk, WkT, 2048, 1024);
    tconv<<<dim3(32, 64), dim3(32, 8), 0, stream>>>(Wv, WvT, 2048, 1024);
    tconv<<<dim3(64, 64), dim3(32, 8), 0, stream>>>(Wo, WoT, 2048, 2048);

    // fused QKV projection: [4096,2048] @ [2048,4096] -> qkvf (f16)
    gemm_f16<_Float16><<<dim3(32, 32), dim3(256), 0, stream>>>(Hh, WqT, qkvf, 4096, 4096, 2048);

    norm_rope<<<dim3(8192), dim3(256), 0, stream>>>(qkvf, 0,    3, 0, q_scale, ct, stb, qn);
    norm_rope<<<dim3(4096), dim3(256), 0, stream>>>(qkvf, 2048, 2, 1, k_scale, ct, stb, kn);
    norm_v_t <<<dim3(128, 4), dim3(256), 0, stream>>>(qkvf, vt);

    attn_fwd<<<dim3(64, 8), dim3(256), 0, stream>>>(qn, kn, vt, attnb);

    gemm_f16<float><<<dim3(16, 32), dim3(256), 0, stream>>>(attnb, WoT, (float*)d_out, 4096, 2048, 2048);
}